// Round 12
// baseline (506.386 us; speedup 1.0000x reference)
//
#include <hip/hip_runtime.h>
#include <math.h>

#define D_MODEL 1024
#define N_HEADS 16
#define D_K 64
#define B_SZ 64
#define S_LEN 2048

// ---------------- kernel 0 (fused q-projection): qt[b,h,d] = (1/8) * sum_j (q[b]@Wq + bq)[h*64+j] * Wk[d, h*64+j] ----------------
// grid 1024 = (b,h), block 256.
__global__ __launch_bounds__(256) void k_qproj(const float* __restrict__ q,
                                               const float* __restrict__ Wq,
                                               const float* __restrict__ bq,
                                               const float* __restrict__ Wk,
                                               float* __restrict__ qt) {
    int b = blockIdx.x >> 4, h = blockIdx.x & 15;
    int t = threadIdx.x;
    __shared__ float ql[D_MODEL];
    __shared__ float qsl[D_K];
    __shared__ float4 red[256];
    ((float4*)ql)[t] = ((const float4*)(q + (size_t)b * D_MODEL))[t];
    __syncthreads();
    // Phase A
    int j4 = t & 15, dg = t >> 4;
    float4 a = make_float4(0.f, 0.f, 0.f, 0.f);
#pragma unroll 8
    for (int i = 0; i < 64; ++i) {
        int d = i * 16 + dg;  // interleaved: wave's 4 dg values hit 4 distinct LDS banks
        float4 w4 = *(const float4*)(Wq + (size_t)d * D_MODEL + h * D_K + 4 * j4);
        float s = ql[d];
        a.x = fmaf(s, w4.x, a.x);
        a.y = fmaf(s, w4.y, a.y);
        a.z = fmaf(s, w4.z, a.z);
        a.w = fmaf(s, w4.w, a.w);
    }
    red[t] = a;
    __syncthreads();
    if (t < 16) {
        float4 r = make_float4(0.f, 0.f, 0.f, 0.f);
#pragma unroll
        for (int g = 0; g < 16; ++g) {
            float4 x = red[g * 16 + t];
            r.x += x.x; r.y += x.y; r.z += x.z; r.w += x.w;
        }
        float4 bb = *(const float4*)(bq + h * D_K + 4 * t);
        r.x += bb.x; r.y += bb.y; r.z += bb.z; r.w += bb.w;
        *(float4*)(qsl + 4 * t) = r;
    }
    __syncthreads();
    // Phase B (verbatim old k_qtil inner)
#pragma unroll
    for (int p = 0; p < 4; ++p) {
        int d = p * 256 + t;
        const float* w = Wk + (size_t)d * D_MODEL + h * D_K;
        float acc = 0.f;
#pragma unroll
        for (int j4i = 0; j4i < 16; ++j4i) {
            float4 w4 = ((const float4*)w)[j4i];
            float4 q4 = ((const float4*)qsl)[j4i];
            acc += w4.x * q4.x + w4.y * q4.y + w4.z * q4.z + w4.w * q4.w;
        }
        qt[((size_t)(b * N_HEADS + h)) * D_MODEL + d] = acc * 0.125f;
    }
}

// ---------------- kernel 1 (fused): scores + per-chunk softmax + attn@v ----------------
// grid 512 = (64 b x 8 s-chunks of 256), block 256 = 4 waves.
// ROUND 12: Phase A made BARRIER-FREE. No k staging in LDS: each lane streams its 4
// k-rows (s = s0+64i+lane) directly from global into registers, fully consuming each
// 128B line over 8 consecutive d-steps (no over-fetch). qt staged into LDS ONCE
// (64 KB, [h][1024]) and read as wave-uniform broadcasts. One barrier in the whole
// kernel before Phase B. FMA order per acc identical to round 6 (ascending d).
#define ST 256
__global__ __launch_bounds__(256) void k_attn(const float* __restrict__ k,
                                              const float* __restrict__ v,
                                              const float* __restrict__ qt,
                                              float* __restrict__ part,
                                              float* __restrict__ ml) {
    __shared__ float qtl[N_HEADS * D_MODEL];  // 64 KB; al aliases first 16 KB after Phase A
    float* al = qtl;
    int b = blockIdx.x >> 3;
    int ch = blockIdx.x & 7;
    int t = threadIdx.x;
    int w = t >> 6, lane = t & 63;
    int s0 = ch * ST;
    const float* kbase = k + ((size_t)b * S_LEN + s0) * D_MODEL;
    const float* qtbase = qt + (size_t)b * N_HEADS * D_MODEL;
    // ---- stage qt[b] fully into LDS once (coalesced, 16 float4/thread) ----
#pragma unroll
    for (int p = 0; p < 16; ++p) {
        int idx = t + 256 * p;                 // 0..4095
        int hh = idx >> 8, d4 = idx & 255;     // head, col4
        *(float4*)(qtl + hh * D_MODEL + 4 * d4) =
            *(const float4*)(qtbase + (size_t)hh * D_MODEL + 4 * d4);
    }
    __syncthreads();
    // ---- Phase A: barrier-free per-lane k-row streaming ----
    float acc[4][4] = {};
    const float* kr0 = kbase + (size_t)(lane) * D_MODEL;
    const float* kr1 = kbase + (size_t)(64 + lane) * D_MODEL;
    const float* kr2 = kbase + (size_t)(128 + lane) * D_MODEL;
    const float* kr3 = kbase + (size_t)(192 + lane) * D_MODEL;
    const float* qw = qtl + (size_t)(4 * w) * D_MODEL;
#pragma unroll 4
    for (int dm = 0; dm < D_MODEL; dm += 4) {
        float4 kv[4];
        kv[0] = *(const float4*)(kr0 + dm);
        kv[1] = *(const float4*)(kr1 + dm);
        kv[2] = *(const float4*)(kr2 + dm);
        kv[3] = *(const float4*)(kr3 + dm);
        float4 qv[4];
#pragma unroll
        for (int j = 0; j < 4; ++j) qv[j] = *(const float4*)(qw + (size_t)j * D_MODEL + dm);  // broadcast
#pragma unroll
        for (int i = 0; i < 4; ++i)
#pragma unroll
            for (int j = 0; j < 4; ++j)
                acc[i][j] = fmaf(kv[i].x, qv[j].x,
                            fmaf(kv[i].y, qv[j].y,
                            fmaf(kv[i].z, qv[j].z,
                            fmaf(kv[i].w, qv[j].w, acc[i][j]))));
    }
    __syncthreads();  // all qtl reads done -> al may reuse the storage
    // ---- Phase B: per-chunk softmax for heads 4w..4w+3 (writes al, aliasing dead qtl) ----
#pragma unroll
    for (int j = 0; j < 4; ++j) {
        float mx = fmaxf(fmaxf(acc[0][j], acc[1][j]), fmaxf(acc[2][j], acc[3][j]));
#pragma unroll
        for (int o = 32; o; o >>= 1) mx = fmaxf(mx, __shfl_xor(mx, o, 64));
        float p0 = __expf(acc[0][j] - mx);
        float p1 = __expf(acc[1][j] - mx);
        float p2 = __expf(acc[2][j] - mx);
        float p3 = __expf(acc[3][j] - mx);
        float l = p0 + p1 + p2 + p3;
#pragma unroll
        for (int o = 32; o; o >>= 1) l += __shfl_xor(l, o, 64);
        int h = 4 * w + j;
        al[h * 256 + lane] = p0;
        al[h * 256 + 64 + lane] = p1;
        al[h * 256 + 128 + lane] = p2;
        al[h * 256 + 192 + lane] = p3;
        if (lane == 0) {
            size_t mi = (((size_t)ch * B_SZ + b) * N_HEADS + h) * 2;
            ml[mi] = mx;
            ml[mi + 1] = l;
        }
    }
    __syncthreads();
    // ---- Phase C: attn @ v (no barriers in loop -> compiler pipelines the v loads) ----
    float4 acc4[N_HEADS];
#pragma unroll
    for (int h = 0; h < N_HEADS; ++h) acc4[h] = make_float4(0.f, 0.f, 0.f, 0.f);
    const float* vbase = v + ((size_t)b * S_LEN + s0) * D_MODEL + 4 * t;
    for (int sg = 0; sg < 64; ++sg) {
        float4 v0 = *(const float4*)(vbase + (size_t)(4 * sg + 0) * D_MODEL);
        float4 v1 = *(const float4*)(vbase + (size_t)(4 * sg + 1) * D_MODEL);
        float4 v2 = *(const float4*)(vbase + (size_t)(4 * sg + 2) * D_MODEL);
        float4 v3 = *(const float4*)(vbase + (size_t)(4 * sg + 3) * D_MODEL);
#pragma unroll
        for (int h = 0; h < N_HEADS; ++h) {
            float4 a4 = *(const float4*)(al + h * 256 + 4 * sg);  // broadcast read
            acc4[h].x = fmaf(a4.x, v0.x, fmaf(a4.y, v1.x, fmaf(a4.z, v2.x, fmaf(a4.w, v3.x, acc4[h].x))));
            acc4[h].y = fmaf(a4.x, v0.y, fmaf(a4.y, v1.y, fmaf(a4.z, v2.y, fmaf(a4.w, v3.y, acc4[h].y))));
            acc4[h].z = fmaf(a4.x, v0.z, fmaf(a4.y, v1.z, fmaf(a4.z, v2.z, fmaf(a4.w, v3.z, acc4[h].z))));
            acc4[h].w = fmaf(a4.x, v0.w, fmaf(a4.y, v1.w, fmaf(a4.z, v2.w, fmaf(a4.w, v3.w, acc4[h].w))));
        }
    }
#pragma unroll
    for (int h = 0; h < N_HEADS; ++h)
        *(float4*)(part + (((size_t)ch * B_SZ + b) * N_HEADS + h) * D_MODEL + 4 * t) = acc4[h];
}

// ---------------- kernel 2: flash-combine chunks + Wv projection ----------------
// grid 1024 = (b,h), block 256.
__global__ __launch_bounds__(256) void k_cc(const float* __restrict__ part,
                                            const float* __restrict__ ml,
                                            const float* __restrict__ Wv,
                                            const float* __restrict__ bv,
                                            float* __restrict__ cc) {
    int b = blockIdx.x >> 4, h = blockIdx.x & 15;
    int t = threadIdx.x;
    __shared__ float vt[D_MODEL];
    __shared__ float4 red[256];
    float m8[8], l8[8];
#pragma unroll
    for (int ch = 0; ch < 8; ++ch) {
        size_t mi = (((size_t)ch * B_SZ + b) * N_HEADS + h) * 2;  // uniform -> scalar loads
        m8[ch] = ml[mi];
        l8[ch] = ml[mi + 1];
    }
    float M = m8[0];
#pragma unroll
    for (int ch = 1; ch < 8; ++ch) M = fmaxf(M, m8[ch]);
    float wgt[8];
    float L = 0.f;
#pragma unroll
    for (int ch = 0; ch < 8; ++ch) {
        wgt[ch] = __expf(m8[ch] - M);
        L = fmaf(l8[ch], wgt[ch], L);
    }
    float invL = 1.0f / L;
    float4 s = make_float4(0.f, 0.f, 0.f, 0.f);
#pragma unroll
    for (int ch = 0; ch < 8; ++ch) {
        float4 x = *(const float4*)(part + (((size_t)ch * B_SZ + b) * N_HEADS + h) * D_MODEL + 4 * t);
        s.x = fmaf(wgt[ch], x.x, s.x);
        s.y = fmaf(wgt[ch], x.y, s.y);
        s.z = fmaf(wgt[ch], x.z, s.z);
        s.w = fmaf(wgt[ch], x.w, s.w);
    }
    s.x *= invL; s.y *= invL; s.z *= invL; s.w *= invL;
    *(float4*)(vt + 4 * t) = s;
    __syncthreads();
    int j4 = t & 15, dg = t >> 4;
    float4 a = make_float4(0.f, 0.f, 0.f, 0.f);
#pragma unroll 8
    for (int i = 0; i < 64; ++i) {
        int d = i * 16 + dg;  // wave's 4 dg -> 4 distinct banks on vt[d]
        float4 w4 = *(const float4*)(Wv + (size_t)d * D_MODEL + h * D_K + 4 * j4);
        float sv = vt[d];
        a.x = fmaf(sv, w4.x, a.x);
        a.y = fmaf(sv, w4.y, a.y);
        a.z = fmaf(sv, w4.z, a.z);
        a.w = fmaf(sv, w4.w, a.w);
    }
    red[t] = a;
    __syncthreads();
    if (t < 16) {
        float4 r = make_float4(0.f, 0.f, 0.f, 0.f);
#pragma unroll
        for (int g = 0; g < 16; ++g) {
            float4 x = red[g * 16 + t];
            r.x += x.x; r.y += x.y; r.z += x.z; r.w += x.w;
        }
        float4 bb = *(const float4*)(bv + h * D_K + 4 * t);
        r.x += bb.x; r.y += bb.y; r.z += bb.z; r.w += bb.w;
        *(float4*)(cc + (size_t)b * D_MODEL + h * D_K + 4 * t) = r;
    }
}

// ---------------- kernel 3: out[b,n] = relu(cc[b,:] @ Wo[:,n] + bo[n]) ----------------
// grid 256 = (64 b x 4 n-chunks), block 256.
__global__ __launch_bounds__(256) void k_out(const float* __restrict__ cc,
                                             const float* __restrict__ Wo,
                                             const float* __restrict__ bo,
                                             float* __restrict__ out) {
    int b = blockIdx.x >> 2, nc = blockIdx.x & 3;
    int t = threadIdx.x;
    __shared__ float cl[D_MODEL];
    __shared__ float4 red[256];
    ((float4*)cl)[t] = ((const float4*)(cc + (size_t)b * D_MODEL))[t];
    __syncthreads();
    int n4 = t & 63, dg = t >> 6;  // dg == wave id -> cl[d] is wave-uniform broadcast
    float4 a = make_float4(0.f, 0.f, 0.f, 0.f);
#pragma unroll 8
    for (int i = 0; i < 256; ++i) {
        int d = dg * 256 + i;
        float4 w4 = *(const float4*)(Wo + (size_t)d * D_MODEL + nc * 256 + 4 * n4);
        float s = cl[d];
        a.x = fmaf(s, w4.x, a.x);
        a.y = fmaf(s, w4.y, a.y);
        a.z = fmaf(s, w4.z, a.z);
        a.w = fmaf(s, w4.w, a.w);
    }
    red[t] = a;
    __syncthreads();
    if (t < 64) {
        float4 r = red[t];
#pragma unroll
        for (int g = 1; g < 4; ++g) {
            float4 x = red[g * 64 + t];
            r.x += x.x; r.y += x.y; r.z += x.z; r.w += x.w;
        }
        float4 bb = *(const float4*)(bo + nc * 256 + 4 * t);
        r.x += bb.x; r.y += bb.y; r.z += bb.z; r.w += bb.w;
        r.x = r.x > 0.f ? r.x : 0.f;
        r.y = r.y > 0.f ? r.y : 0.f;
        r.z = r.z > 0.f ? r.z : 0.f;
        r.w = r.w > 0.f ? r.w : 0.f;
        *(float4*)(out + (size_t)b * D_MODEL + nc * 256 + 4 * t) = r;
    }
}

extern "C" void kernel_launch(void* const* d_in, const int* in_sizes, int n_in,
                              void* d_out, int out_size, void* d_ws, size_t ws_size,
                              hipStream_t stream) {
    const float* q  = (const float*)d_in[0];
    const float* k  = (const float*)d_in[1];
    const float* v  = (const float*)d_in[2];
    const float* Wq = (const float*)d_in[3];
    const float* bq = (const float*)d_in[4];
    const float* Wk = (const float*)d_in[5];
    // d_in[6] = bk: unused — softmax is shift-invariant, qh.bk is constant per (b,h) row
    const float* Wv = (const float*)d_in[7];
    const float* bv = (const float*)d_in[8];
    const float* Wo = (const float*)d_in[9];
    const float* bo = (const float*)d_in[10];
    float* out = (float*)d_out;

    float* ws = (float*)d_ws;
    float* qt   = ws;                       // 1048576 floats
    float* part = qt + 1048576;             // 8388608
    float* ml   = part + 8388608;           // 16384
    float* cc   = ml + 16384;               // 65536   (total ~38 MB)

    k_qproj<<<1024, 256, 0, stream>>>(q, Wq, bq, Wk, qt);
    k_attn<<<512, 256, 0, stream>>>(k, v, qt, part, ml);
    k_cc<<<1024, 256, 0, stream>>>(part, ml, Wv, bv, cc);
    k_out<<<256, 256, 0, stream>>>(cc, Wo, bo, out);
}

// Round 13
// 332.085 us; speedup vs baseline: 1.5249x; 1.5249x over previous
//
#include <hip/hip_runtime.h>
#include <math.h>

#define D_MODEL 1024
#define N_HEADS 16
#define D_K 64
#define B_SZ 64
#define S_LEN 2048

// ---------------- kernel 0 (fused q-projection): qt[b,h,d] = (1/8) * sum_j (q[b]@Wq + bq)[h*64+j] * Wk[d, h*64+j] ----------------
// grid 1024 = (b,h), block 256.
__global__ __launch_bounds__(256) void k_qproj(const float* __restrict__ q,
                                               const float* __restrict__ Wq,
                                               const float* __restrict__ bq,
                                               const float* __restrict__ Wk,
                                               float* __restrict__ qt) {
    int b = blockIdx.x >> 4, h = blockIdx.x & 15;
    int t = threadIdx.x;
    __shared__ float ql[D_MODEL];
    __shared__ float qsl[D_K];
    __shared__ float4 red[256];
    ((float4*)ql)[t] = ((const float4*)(q + (size_t)b * D_MODEL))[t];
    __syncthreads();
    // Phase A
    int j4 = t & 15, dg = t >> 4;
    float4 a = make_float4(0.f, 0.f, 0.f, 0.f);
#pragma unroll 8
    for (int i = 0; i < 64; ++i) {
        int d = i * 16 + dg;  // interleaved: wave's 4 dg values hit 4 distinct LDS banks
        float4 w4 = *(const float4*)(Wq + (size_t)d * D_MODEL + h * D_K + 4 * j4);
        float s = ql[d];
        a.x = fmaf(s, w4.x, a.x);
        a.y = fmaf(s, w4.y, a.y);
        a.z = fmaf(s, w4.z, a.z);
        a.w = fmaf(s, w4.w, a.w);
    }
    red[t] = a;
    __syncthreads();
    if (t < 16) {
        float4 r = make_float4(0.f, 0.f, 0.f, 0.f);
#pragma unroll
        for (int g = 0; g < 16; ++g) {
            float4 x = red[g * 16 + t];
            r.x += x.x; r.y += x.y; r.z += x.z; r.w += x.w;
        }
        float4 bb = *(const float4*)(bq + h * D_K + 4 * t);
        r.x += bb.x; r.y += bb.y; r.z += bb.z; r.w += bb.w;
        *(float4*)(qsl + 4 * t) = r;
    }
    __syncthreads();
    // Phase B (verbatim old k_qtil inner)
#pragma unroll
    for (int p = 0; p < 4; ++p) {
        int d = p * 256 + t;
        const float* w = Wk + (size_t)d * D_MODEL + h * D_K;
        float acc = 0.f;
#pragma unroll
        for (int j4i = 0; j4i < 16; ++j4i) {
            float4 w4 = ((const float4*)w)[j4i];
            float4 q4 = ((const float4*)qsl)[j4i];
            acc += w4.x * q4.x + w4.y * q4.y + w4.z * q4.z + w4.w * q4.w;
        }
        qt[((size_t)(b * N_HEADS + h)) * D_MODEL + d] = acc * 0.125f;
    }
}

// ---------------- kernel 1 (fused, CHAMPION = round 6): scores + per-chunk softmax + attn@v ----------------
// grid 512 = (64 b x 8 s-chunks of 256), block 256 = 4 waves.
// Best of 7 measured Phase-A structures (~265 µs): 2-barrier staged loop, ST=256,
// DC=32, KROW=36 pad; al aliases kt's LDS after Phase A (38 KB total).
#define ST 256
#define DC 32
#define KROW 36  // 32 + 4 pad: conflict-free b128 reads (quad = 9*row % 8)
__global__ __launch_bounds__(256) void k_attn(const float* __restrict__ k,
                                              const float* __restrict__ v,
                                              const float* __restrict__ qt,
                                              float* __restrict__ part,
                                              float* __restrict__ ml) {
    __shared__ float smem[ST * KROW];        // 36 KB: kt (Phase A) / al (Phase B,C)
    __shared__ float qtl[N_HEADS * DC];      // 2 KB   (total 38 KB)
    float* kt = smem;
    float* al = smem;  // alias: first 16 KB reused after Phase A
    int b = blockIdx.x >> 3;
    int ch = blockIdx.x & 7;
    int t = threadIdx.x;
    int w = t >> 6, lane = t & 63;
    int s0 = ch * ST;
    const float* kbase = k + ((size_t)b * S_LEN + s0) * D_MODEL;
    const float* qtbase = qt + (size_t)b * N_HEADS * D_MODEL;
    // ---- Phase A: scores ----
    float acc[4][4] = {};
    for (int dc = 0; dc < D_MODEL; dc += DC) {
#pragma unroll
        for (int p = 0; p < 8; ++p) {
            int idx = t + 256 * p;
            int s = idx >> 3, d4 = idx & 7;
            float4 v4 = *(const float4*)(kbase + (size_t)s * D_MODEL + dc + 4 * d4);
            *(float4*)(kt + s * KROW + 4 * d4) = v4;
        }
        if (t < 128) {
            int hh = t >> 3, d4 = t & 7;
            *(float4*)(qtl + hh * DC + 4 * d4) =
                *(const float4*)(qtbase + (size_t)hh * D_MODEL + dc + 4 * d4);
        }
        __syncthreads();
#pragma unroll
        for (int d4 = 0; d4 < DC / 4; ++d4) {
            float4 qv[4], kv[4];
#pragma unroll
            for (int j = 0; j < 4; ++j) qv[j] = *(const float4*)(qtl + (4 * w + j) * DC + 4 * d4);
#pragma unroll
            for (int i = 0; i < 4; ++i) kv[i] = *(const float4*)(kt + (64 * i + lane) * KROW + 4 * d4);
#pragma unroll
            for (int i = 0; i < 4; ++i)
#pragma unroll
                for (int j = 0; j < 4; ++j)
                    acc[i][j] = fmaf(kv[i].x, qv[j].x,
                                fmaf(kv[i].y, qv[j].y,
                                fmaf(kv[i].z, qv[j].z,
                                fmaf(kv[i].w, qv[j].w, acc[i][j]))));
        }
        __syncthreads();  // after final iter: all kt reads done -> al may reuse the storage
    }
    // ---- Phase B: per-chunk softmax for heads 4w..4w+3 (writes al, aliasing dead kt) ----
#pragma unroll
    for (int j = 0; j < 4; ++j) {
        float mx = fmaxf(fmaxf(acc[0][j], acc[1][j]), fmaxf(acc[2][j], acc[3][j]));
#pragma unroll
        for (int o = 32; o; o >>= 1) mx = fmaxf(mx, __shfl_xor(mx, o, 64));
        float p0 = __expf(acc[0][j] - mx);
        float p1 = __expf(acc[1][j] - mx);
        float p2 = __expf(acc[2][j] - mx);
        float p3 = __expf(acc[3][j] - mx);
        float l = p0 + p1 + p2 + p3;
#pragma unroll
        for (int o = 32; o; o >>= 1) l += __shfl_xor(l, o, 64);
        int h = 4 * w + j;
        al[h * 256 + lane] = p0;
        al[h * 256 + 64 + lane] = p1;
        al[h * 256 + 128 + lane] = p2;
        al[h * 256 + 192 + lane] = p3;
        if (lane == 0) {
            size_t mi = (((size_t)ch * B_SZ + b) * N_HEADS + h) * 2;
            ml[mi] = mx;
            ml[mi + 1] = l;
        }
    }
    __syncthreads();
    // ---- Phase C: attn @ v (no barriers in loop -> compiler pipelines the v loads) ----
    float4 acc4[N_HEADS];
#pragma unroll
    for (int h = 0; h < N_HEADS; ++h) acc4[h] = make_float4(0.f, 0.f, 0.f, 0.f);
    const float* vbase = v + ((size_t)b * S_LEN + s0) * D_MODEL + 4 * t;
    for (int sg = 0; sg < 64; ++sg) {
        float4 v0 = *(const float4*)(vbase + (size_t)(4 * sg + 0) * D_MODEL);
        float4 v1 = *(const float4*)(vbase + (size_t)(4 * sg + 1) * D_MODEL);
        float4 v2 = *(const float4*)(vbase + (size_t)(4 * sg + 2) * D_MODEL);
        float4 v3 = *(const float4*)(vbase + (size_t)(4 * sg + 3) * D_MODEL);
#pragma unroll
        for (int h = 0; h < N_HEADS; ++h) {
            float4 a4 = *(const float4*)(al + h * 256 + 4 * sg);  // broadcast read
            acc4[h].x = fmaf(a4.x, v0.x, fmaf(a4.y, v1.x, fmaf(a4.z, v2.x, fmaf(a4.w, v3.x, acc4[h].x))));
            acc4[h].y = fmaf(a4.x, v0.y, fmaf(a4.y, v1.y, fmaf(a4.z, v2.y, fmaf(a4.w, v3.y, acc4[h].y))));
            acc4[h].z = fmaf(a4.x, v0.z, fmaf(a4.y, v1.z, fmaf(a4.z, v2.z, fmaf(a4.w, v3.z, acc4[h].z))));
            acc4[h].w = fmaf(a4.x, v0.w, fmaf(a4.y, v1.w, fmaf(a4.z, v2.w, fmaf(a4.w, v3.w, acc4[h].w))));
        }
    }
#pragma unroll
    for (int h = 0; h < N_HEADS; ++h)
        *(float4*)(part + (((size_t)ch * B_SZ + b) * N_HEADS + h) * D_MODEL + 4 * t) = acc4[h];
}

// ---------------- kernel 2: flash-combine chunks + Wv projection ----------------
// grid 1024 = (b,h), block 256.
__global__ __launch_bounds__(256) void k_cc(const float* __restrict__ part,
                                            const float* __restrict__ ml,
                                            const float* __restrict__ Wv,
                                            const float* __restrict__ bv,
                                            float* __restrict__ cc) {
    int b = blockIdx.x >> 4, h = blockIdx.x & 15;
    int t = threadIdx.x;
    __shared__ float vt[D_MODEL];
    __shared__ float4 red[256];
    float m8[8], l8[8];
#pragma unroll
    for (int ch = 0; ch < 8; ++ch) {
        size_t mi = (((size_t)ch * B_SZ + b) * N_HEADS + h) * 2;  // uniform -> scalar loads
        m8[ch] = ml[mi];
        l8[ch] = ml[mi + 1];
    }
    float M = m8[0];
#pragma unroll
    for (int ch = 1; ch < 8; ++ch) M = fmaxf(M, m8[ch]);
    float wgt[8];
    float L = 0.f;
#pragma unroll
    for (int ch = 0; ch < 8; ++ch) {
        wgt[ch] = __expf(m8[ch] - M);
        L = fmaf(l8[ch], wgt[ch], L);
    }
    float invL = 1.0f / L;
    float4 s = make_float4(0.f, 0.f, 0.f, 0.f);
#pragma unroll
    for (int ch = 0; ch < 8; ++ch) {
        float4 x = *(const float4*)(part + (((size_t)ch * B_SZ + b) * N_HEADS + h) * D_MODEL + 4 * t);
        s.x = fmaf(wgt[ch], x.x, s.x);
        s.y = fmaf(wgt[ch], x.y, s.y);
        s.z = fmaf(wgt[ch], x.z, s.z);
        s.w = fmaf(wgt[ch], x.w, s.w);
    }
    s.x *= invL; s.y *= invL; s.z *= invL; s.w *= invL;
    *(float4*)(vt + 4 * t) = s;
    __syncthreads();
    int j4 = t & 15, dg = t >> 4;
    float4 a = make_float4(0.f, 0.f, 0.f, 0.f);
#pragma unroll 8
    for (int i = 0; i < 64; ++i) {
        int d = i * 16 + dg;  // wave's 4 dg -> 4 distinct banks on vt[d]
        float4 w4 = *(const float4*)(Wv + (size_t)d * D_MODEL + h * D_K + 4 * j4);
        float sv = vt[d];
        a.x = fmaf(sv, w4.x, a.x);
        a.y = fmaf(sv, w4.y, a.y);
        a.z = fmaf(sv, w4.z, a.z);
        a.w = fmaf(sv, w4.w, a.w);
    }
    red[t] = a;
    __syncthreads();
    if (t < 16) {
        float4 r = make_float4(0.f, 0.f, 0.f, 0.f);
#pragma unroll
        for (int g = 0; g < 16; ++g) {
            float4 x = red[g * 16 + t];
            r.x += x.x; r.y += x.y; r.z += x.z; r.w += x.w;
        }
        float4 bb = *(const float4*)(bv + h * D_K + 4 * t);
        r.x += bb.x; r.y += bb.y; r.z += bb.z; r.w += bb.w;
        *(float4*)(cc + (size_t)b * D_MODEL + h * D_K + 4 * t) = r;
    }
}

// ---------------- kernel 3: out[b,n] = relu(cc[b,:] @ Wo[:,n] + bo[n]) ----------------
// grid 256 = (64 b x 4 n-chunks), block 256.
__global__ __launch_bounds__(256) void k_out(const float* __restrict__ cc,
                                             const float* __restrict__ Wo,
                                             const float* __restrict__ bo,
                                             float* __restrict__ out) {
    int b = blockIdx.x >> 2, nc = blockIdx.x & 3;
    int t = threadIdx.x;
    __shared__ float cl[D_MODEL];
    __shared__ float4 red[256];
    ((float4*)cl)[t] = ((const float4*)(cc + (size_t)b * D_MODEL))[t];
    __syncthreads();
    int n4 = t & 63, dg = t >> 6;  // dg == wave id -> cl[d] is wave-uniform broadcast
    float4 a = make_float4(0.f, 0.f, 0.f, 0.f);
#pragma unroll 8
    for (int i = 0; i < 256; ++i) {
        int d = dg * 256 + i;
        float4 w4 = *(const float4*)(Wo + (size_t)d * D_MODEL + nc * 256 + 4 * n4);
        float s = cl[d];
        a.x = fmaf(s, w4.x, a.x);
        a.y = fmaf(s, w4.y, a.y);
        a.z = fmaf(s, w4.z, a.z);
        a.w = fmaf(s, w4.w, a.w);
    }
    red[t] = a;
    __syncthreads();
    if (t < 64) {
        float4 r = red[t];
#pragma unroll
        for (int g = 1; g < 4; ++g) {
            float4 x = red[g * 64 + t];
            r.x += x.x; r.y += x.y; r.z += x.z; r.w += x.w;
        }
        float4 bb = *(const float4*)(bo + nc * 256 + 4 * t);
        r.x += bb.x; r.y += bb.y; r.z += bb.z; r.w += bb.w;
        r.x = r.x > 0.f ? r.x : 0.f;
        r.y = r.y > 0.f ? r.y : 0.f;
        r.z = r.z > 0.f ? r.z : 0.f;
        r.w = r.w > 0.f ? r.w : 0.f;
        *(float4*)(out + (size_t)b * D_MODEL + nc * 256 + 4 * t) = r;
    }
}

extern "C" void kernel_launch(void* const* d_in, const int* in_sizes, int n_in,
                              void* d_out, int out_size, void* d_ws, size_t ws_size,
                              hipStream_t stream) {
    const float* q  = (const float*)d_in[0];
    const float* k  = (const float*)d_in[1];
    const float* v  = (const float*)d_in[2];
    const float* Wq = (const float*)d_in[3];
    const float* bq = (const float*)d_in[4];
    const float* Wk = (const float*)d_in[5];
    // d_in[6] = bk: unused — softmax is shift-invariant, qh.bk is constant per (b,h) row
    const float* Wv = (const float*)d_in[7];
    const float* bv = (const float*)d_in[8];
    const float* Wo = (const float*)d_in[9];
    const float* bo = (const float*)d_in[10];
    float* out = (float*)d_out;

    float* ws = (float*)d_ws;
    float* qt   = ws;                       // 1048576 floats
    float* part = qt + 1048576;             // 8388608
    float* ml   = part + 8388608;           // 16384
    float* cc   = ml + 16384;               // 65536   (total ~38 MB)

    k_qproj<<<1024, 256, 0, stream>>>(q, Wq, bq, Wk, qt);
    k_attn<<<512, 256, 0, stream>>>(k, v, qt, part, ml);
    k_cc<<<1024, 256, 0, stream>>>(part, ml, Wv, bv, cc);
    k_out<<<256, 256, 0, stream>>>(cc, Wo, bo, out);
}